// Round 12
// baseline (102.996 us; speedup 1.0000x reference)
//
#include <hip/hip_runtime.h>
#include <stdint.h>

typedef short short8 __attribute__((ext_vector_type(8)));
typedef float f32x4 __attribute__((ext_vector_type(4)));
typedef float f32x2 __attribute__((ext_vector_type(2)));
typedef long lng2 __attribute__((ext_vector_type(2)));

#define B_TOTAL 8192
#define DDIM 256            // k elements; 1 byte each in fp8
#define BM 256
#define BN 64
#define NSPLIT 16
#define COLS_PER (B_TOTAL / NSPLIT)        // 512
#define ITERS (COLS_PER / BN)              // 8
#define NBLOCKS ((B_TOTAL / BM) * NSPLIT)  // 512 blocks x 512 thr
// sqrt((1/T)/ln2): fold temperature+log2e into the fp8 embeddings (both operands)
#define SCALE_HALF 3.79828546f
#define LN2F 0.6931471805599453f

typedef __attribute__((address_space(3))) char lds_char;
typedef __attribute__((address_space(1))) const char gbl_char;

// ---- prep: fp32->fp8 e4m3 (scaled, k-permuted rows), label pack, zeroing ----
// within each row: orig k = kw*32 + g*8 + e  ->  byte pos p = g*64 + kw*8 + e
// so a lane's 8-byte MFMA fragments for consecutive k-windows are contiguous.
__global__ __launch_bounds__(256) void prep_all(
    const float* __restrict__ E, const int* __restrict__ lab,
    unsigned char* __restrict__ Eb8, unsigned int* __restrict__ plab,
    float* __restrict__ posAll) {
  const int t = blockIdx.x * 256 + threadIdx.x;   // 262144 threads, 8 floats each
  const float4* s4 = (const float4*)E + (size_t)t * 2;
  float4 v0 = s4[0], v1 = s4[1];
  unsigned int d0 = (unsigned int)__builtin_amdgcn_cvt_pk_fp8_f32(
      v0.x * SCALE_HALF, v0.y * SCALE_HALF, 0, false);
  d0 = (unsigned int)__builtin_amdgcn_cvt_pk_fp8_f32(
      v0.z * SCALE_HALF, v0.w * SCALE_HALF, (int)d0, true);
  unsigned int d1 = (unsigned int)__builtin_amdgcn_cvt_pk_fp8_f32(
      v1.x * SCALE_HALF, v1.y * SCALE_HALF, 0, false);
  d1 = (unsigned int)__builtin_amdgcn_cvt_pk_fp8_f32(
      v1.z * SCALE_HALF, v1.w * SCALE_HALF, (int)d1, true);
  const int row = t >> 5, j = t & 31;             // j-th group of 8 consecutive k
  unsigned char* orow = Eb8 + (size_t)row * DDIM + ((j & 3) * 64 + (j >> 2) * 8);
  *(unsigned long long*)orow =
      (unsigned long long)d0 | ((unsigned long long)d1 << 32);
  if (t < B_TOTAL) {
    int4 l = ((const int4*)lab)[t];   // labels arrive as int32
    // positional one-hot: aspect a (value 0..5) occupies bits [6a, 6a+6)
    plab[t] = (1u << ((unsigned)l.x & 31u))
            | (1u << (((unsigned)l.y & 31u) + 6u))
            | (1u << (((unsigned)l.z & 31u) + 12u))
            | (1u << (((unsigned)l.w & 31u) + 18u));
  }
  if (t < 2 * B_TOTAL) posAll[t] = 0.0f;   // posArr+allArr contiguous
}

// ---- fused sim/exp/mask/rowsum: 8 waves x 32 rows, fp8 MFMA, 2-phase dbuf ---
struct __align__(16) SMem {
  char btile[2][BN * DDIM];          // 2 x 16 KB fp8, XOR-swizzled 16B chunks
  unsigned int plab_all[COLS_PER];   // 2 KB: packed labels for the whole panel
};

template <int DIAG>
__device__ __forceinline__ void epi_n(
    const f32x4 (&acc)[2], int n, int colbase, int itBN, int l15,
    const unsigned int (&pi)[2][4], const int (&irow)[2][4],
    const unsigned int* __restrict__ plab_all,
    f32x2 (&pos2)[2][2], f32x2 (&all2)[2][2]) {
  const int j = colbase + n * 16 + l15;
  const unsigned int hj = plab_all[itBN + n * 16 + l15];
#pragma unroll
  for (int m = 0; m < 2; ++m) {
    float e[4];
#pragma unroll
    for (int q = 0; q < 4; ++q) {
      float v = __builtin_amdgcn_exp2f(acc[m][q]);   // acc already scaled
      if (DIAG) { if (j == irow[m][q]) v = 0.0f; }
      e[q] = v;
    }
    f32x2 p01 = { (pi[m][0] & hj) ? e[0] : 0.0f, (pi[m][1] & hj) ? e[1] : 0.0f };
    f32x2 p23 = { (pi[m][2] & hj) ? e[2] : 0.0f, (pi[m][3] & hj) ? e[3] : 0.0f };
    all2[m][0] += (f32x2){e[0], e[1]};
    all2[m][1] += (f32x2){e[2], e[3]};
    pos2[m][0] += p01;
    pos2[m][1] += p23;
  }
}

template <int DIAG>
__device__ __forceinline__ void iter_body(
    const char* __restrict__ btile, const unsigned int* __restrict__ plab_all,
    const long (&afrag)[2][8], const unsigned int (&pi)[2][4],
    const int (&irow)[2][4], int colbase, int itBN, int l15, int l4,
    f32x2 (&pos2)[2][2], f32x2 (&all2)[2][2]) {
  auto kloop = [&](int n, f32x4 (&acc)[2]) {
    acc[0] = (f32x4){0.f, 0.f, 0.f, 0.f};
    acc[1] = (f32x4){0.f, 0.f, 0.f, 0.f};
    const unsigned int rr = (unsigned int)(n * 16 + l15);
#pragma unroll
    for (int kw8 = 0; kw8 < 4; ++kw8) {             // 4 x b128, each = 2 k-windows
      const unsigned int c = (unsigned int)(l4 * 4 + kw8);   // chunk in row
      const unsigned int s = c ^ (rr & 7u);                  // swizzled
      lng2 b2 = *(const lng2*)(btile + rr * 256u + s * 16u);
      acc[0] = __builtin_amdgcn_mfma_f32_16x16x32_fp8_fp8(
          afrag[0][kw8 * 2], b2[0], acc[0], 0, 0, 0);
      acc[1] = __builtin_amdgcn_mfma_f32_16x16x32_fp8_fp8(
          afrag[1][kw8 * 2], b2[0], acc[1], 0, 0, 0);
      acc[0] = __builtin_amdgcn_mfma_f32_16x16x32_fp8_fp8(
          afrag[0][kw8 * 2 + 1], b2[1], acc[0], 0, 0, 0);
      acc[1] = __builtin_amdgcn_mfma_f32_16x16x32_fp8_fp8(
          afrag[1][kw8 * 2 + 1], b2[1], acc[1], 0, 0, 0);
    }
  };
  // NOTE: no s_setprio here. Theory: setprio(1) during the MFMA/kloop phase
  // starves prio-0 epilogue waves (CU-wide, across blocks) -> chip-wide
  // kloop/epilogue serialization = the measured pipes-sum signature.
  f32x4 accA[2], accB[2];
  kloop(0, accA);
  kloop(1, accB);
  epi_n<DIAG>(accA, 0, colbase, itBN, l15, pi, irow, plab_all, pos2, all2);
  kloop(2, accA);
  epi_n<DIAG>(accB, 1, colbase, itBN, l15, pi, irow, plab_all, pos2, all2);
  kloop(3, accB);
  epi_n<DIAG>(accA, 2, colbase, itBN, l15, pi, irow, plab_all, pos2, all2);
  epi_n<DIAG>(accB, 3, colbase, itBN, l15, pi, irow, plab_all, pos2, all2);
}

__global__ __launch_bounds__(512, 2) void main_kernel(
    const unsigned char* __restrict__ Eb8, const unsigned int* __restrict__ plab,
    float* __restrict__ posArr, float* __restrict__ allArr) {
  __shared__ SMem sm;
  const int tid = threadIdx.x;
  const int lane = tid & 63;
  const int wid = tid >> 6;        // 8 waves, each owns 32 rows
  const int l15 = lane & 15;
  const int l4 = lane >> 4;
  const int rb = (int)blockIdx.x & 31;   // 32 row-blocks of 256
  const int cs = (int)blockIdx.x >> 5;   // 16 column panels of 512
  const int rowbase = rb * BM;
  const int colstart = cs * COLS_PER;

  // stage helper: 16 KB fp8 tile, 2 x global_load_lds(16B) per thread (512 thr)
  // linear LDS dest (wave-uniform base + lane*16), inverse-swizzled global src
  // (rule #21); read side applies the same XOR.
  auto stage = [&](int bufi, int cb) {
#pragma unroll
    for (int q = 0; q < 2; ++q) {
      const unsigned int base = (unsigned int)q * 8192u + (unsigned int)wid * 1024u;
      const unsigned int L = base + (unsigned int)lane * 16u;
      const unsigned int r = L >> 8;          // tile row / output column (0..63)
      const unsigned int s = (L >> 4) & 15u;  // stored 16B chunk in row
      const unsigned int c = s ^ (r & 7u);    // logical chunk (involution)
      const char* src = (const char*)(Eb8 + (size_t)(cb + (int)r) * DDIM + c * 16);
      char* dst = sm.btile[bufi] + base;
      __builtin_amdgcn_global_load_lds((gbl_char*)src, (lds_char*)dst, 16, 0, 0);
    }
  };

  // prologue: issue tile 0 staging first (hide L2 latency under setup below)
  stage(0, colstart);

  // A fragments: register-resident, 32 rows x 256 k per wave (32 VGPR in fp8)
  long afrag[2][8];
#pragma unroll
  for (int m = 0; m < 2; ++m) {
    const int row = rowbase + wid * 32 + m * 16 + l15;
    const char* rp = (const char*)Eb8 + (size_t)row * DDIM + l4 * 64;
#pragma unroll
    for (int kw8 = 0; kw8 < 4; ++kw8) {
      lng2 t = *(const lng2*)(rp + kw8 * 16);
      afrag[m][kw8 * 2] = t[0];
      afrag[m][kw8 * 2 + 1] = t[1];
    }
  }

  // panel labels -> LDS once (keeps the in-loop vmcnt count pure: stage only)
  sm.plab_all[tid] = plab[colstart + tid];

  unsigned int pi[2][4];
  int irow[2][4];
#pragma unroll
  for (int m = 0; m < 2; ++m)
#pragma unroll
    for (int q = 0; q < 4; ++q) {
      const int i = rowbase + wid * 32 + m * 16 + l4 * 4 + q;
      irow[m][q] = i;
      pi[m][q] = plab[i];
    }

  // drain ALL prologue memory ops so the in-loop counted vmcnt is exact
  asm volatile("s_waitcnt vmcnt(0) lgkmcnt(0)" ::: "memory");
  __builtin_amdgcn_s_barrier();            // tile0 + labels visible to all waves
  __builtin_amdgcn_sched_barrier(0);

  f32x2 pos2[2][2] = {};
  f32x2 all2[2][2] = {};

  for (int it = 0; it < ITERS; ++it) {
    const int colbase = colstart + it * BN;
    const int cur = it & 1;

    if (it + 1 < ITERS) {
      stage(cur ^ 1, colbase + BN);                     // issue next tile (2/thread)
      asm volatile("s_waitcnt vmcnt(2)" ::: "memory");  // current tile landed
    } else {
      asm volatile("s_waitcnt vmcnt(0)" ::: "memory");  // final tile: full drain
    }
    __builtin_amdgcn_s_barrier();                       // all waves' shares landed
    __builtin_amdgcn_sched_barrier(0);

    const bool hasDiag = (colbase < rowbase + BM) && (rowbase < colbase + BN);
    if (hasDiag)
      iter_body<1>(sm.btile[cur], sm.plab_all, afrag, pi, irow,
                   colbase, it * BN, l15, l4, pos2, all2);
    else
      iter_body<0>(sm.btile[cur], sm.plab_all, afrag, pi, irow,
                   colbase, it * BN, l15, l4, pos2, all2);

    __builtin_amdgcn_s_barrier();   // all waves done reading btile[cur]
    __builtin_amdgcn_sched_barrier(0);
  }

  // reduce across the 16 lanes sharing the same rows, then one atomic per row
#pragma unroll
  for (int m = 0; m < 2; ++m)
#pragma unroll
    for (int q = 0; q < 4; ++q) {
      float p = pos2[m][q >> 1][q & 1], al = all2[m][q >> 1][q & 1];
      p += __shfl_xor(p, 1); p += __shfl_xor(p, 2);
      p += __shfl_xor(p, 4); p += __shfl_xor(p, 8);
      al += __shfl_xor(al, 1); al += __shfl_xor(al, 2);
      al += __shfl_xor(al, 4); al += __shfl_xor(al, 8);
      if (l15 == 0) {
        atomicAdd(&posArr[irow[m][q]], p);
        atomicAdd(&allArr[irow[m][q]], al);
      }
    }
}

// ---- finalize: row losses + mean (separate launch = free ordering) ----------
__global__ __launch_bounds__(1024) void finalize_kernel(
    const float* __restrict__ posArr, const float* __restrict__ allArr,
    float* __restrict__ out) {
  float ls = 0.f, cnt = 0.f;
#pragma unroll
  for (int k = 0; k < B_TOTAL / 1024; ++k) {
    const int i = threadIdx.x + (k << 10);
    const float p = posArr[i];
    const float a = allArr[i];
    if (p > 0.f) {
      ls += (__builtin_amdgcn_logf(a + 1e-8f) - __builtin_amdgcn_logf(p)) * LN2F;
      cnt += 1.f;
    }
  }
#pragma unroll
  for (int msk = 1; msk < 64; msk <<= 1) {
    ls += __shfl_xor(ls, msk);
    cnt += __shfl_xor(cnt, msk);
  }
  __shared__ float sls[16], scnt[16];
  const int w = threadIdx.x >> 6;
  if ((threadIdx.x & 63) == 0) { sls[w] = ls; scnt[w] = cnt; }
  __syncthreads();
  if (threadIdx.x == 0) {
    float L = 0.f, C = 0.f;
    for (int i = 0; i < 16; ++i) { L += sls[i]; C += scnt[i]; }
    out[0] = (C > 0.f) ? L / fmaxf(C, 1.f) : 0.f;
  }
}

// ---- launch -----------------------------------------------------------------
extern "C" void kernel_launch(void* const* d_in, const int* in_sizes, int n_in,
                              void* d_out, int out_size, void* d_ws, size_t ws_size,
                              hipStream_t stream) {
  const float* E = (const float*)d_in[0];
  const int* lab = (const int*)d_in[1];
  float* out = (float*)d_out;
  char* ws = (char*)d_ws;

  unsigned char* Eb8 = (unsigned char*)ws;                        // 2 MB
  unsigned int* plab = (unsigned int*)(ws + 2u * 1024u * 1024u);  // 32 KB
  float* posArr = (float*)(ws + 2u * 1024u * 1024u + 32u * 1024u);
  float* allArr = posArr + B_TOTAL;

  prep_all<<<1024, 256, 0, stream>>>(E, lab, Eb8, plab, posArr);
  main_kernel<<<NBLOCKS, 512, 0, stream>>>(Eb8, plab, posArr, allArr);
  finalize_kernel<<<1, 1024, 0, stream>>>(posArr, allArr, out);
}

// Round 13
// 97.922 us; speedup vs baseline: 1.0518x; 1.0518x over previous
//
#include <hip/hip_runtime.h>
#include <stdint.h>

typedef float f32x4 __attribute__((ext_vector_type(4)));
typedef float f32x2 __attribute__((ext_vector_type(2)));
typedef long lng2 __attribute__((ext_vector_type(2)));

#define B_TOTAL 8192
#define DDIM 256            // k elements; 1 byte each in fp8
#define BM 128              // rows per block (4 waves x 32)
#define BN 64               // cols per iter
#define NSPLIT 16
#define COLS_PER (B_TOTAL / NSPLIT)        // 512
#define ITERS (COLS_PER / BN)              // 8
#define NBLOCKS ((B_TOTAL / BM) * NSPLIT)  // 1024 blocks x 256 thr
// sqrt((1/T)/ln2): fold temperature+log2e into the fp8 embeddings (both operands)
#define SCALE_HALF 3.79828546f
#define LN2F 0.6931471805599453f

// ---- prep: fp32->fp8 e4m3, two layouts (A row-perm, B fragment-major) -------
// A layout (EbA): row-major rows, within row byte p = g*64 + kw*8 + e for
//   original k = kw*32 + g*8 + e (g = k-group = lane>>4 of consumer).
// B layout (Bf): fragment-major: 16-col tile ct, k-window-pair kw8, lane(l15,l4):
//   byte = ct*4096 + kw8*1024 + l4*256 + l15*16 + half*8  (half = kw&1)
//   -> a wave's b128 fragment load is uniform_base + lane*16 (perfect coalesce).
__global__ __launch_bounds__(256) void prep_all(
    const float* __restrict__ E, const int* __restrict__ lab,
    unsigned char* __restrict__ EbA, unsigned char* __restrict__ Bf,
    unsigned int* __restrict__ plab, float* __restrict__ posAll) {
  const int t = blockIdx.x * 256 + threadIdx.x;   // 262144 threads, 8 floats each
  const float4* s4 = (const float4*)E + (size_t)t * 2;
  float4 v0 = s4[0], v1 = s4[1];
  unsigned int d0 = (unsigned int)__builtin_amdgcn_cvt_pk_fp8_f32(
      v0.x * SCALE_HALF, v0.y * SCALE_HALF, 0, false);
  d0 = (unsigned int)__builtin_amdgcn_cvt_pk_fp8_f32(
      v0.z * SCALE_HALF, v0.w * SCALE_HALF, (int)d0, true);
  unsigned int d1 = (unsigned int)__builtin_amdgcn_cvt_pk_fp8_f32(
      v1.x * SCALE_HALF, v1.y * SCALE_HALF, 0, false);
  d1 = (unsigned int)__builtin_amdgcn_cvt_pk_fp8_f32(
      v1.z * SCALE_HALF, v1.w * SCALE_HALF, (int)d1, true);
  const unsigned long long v8 =
      (unsigned long long)d0 | ((unsigned long long)d1 << 32);
  const int row = t >> 5, j = t & 31;             // j-th group of 8 consecutive k
  // A layout
  *(unsigned long long*)(EbA + (size_t)row * DDIM + ((j & 3) * 64 + (j >> 2) * 8)) = v8;
  // B fragment-major layout
  const unsigned int boff = (unsigned int)(row >> 4) * 4096u +
                            (unsigned int)(j >> 3) * 1024u +
                            (unsigned int)(j & 3) * 256u +
                            (unsigned int)(row & 15) * 16u +
                            (unsigned int)((j >> 2) & 1) * 8u;
  *(unsigned long long*)(Bf + boff) = v8;
  if (t < B_TOTAL) {
    int4 l = ((const int4*)lab)[t];   // labels arrive as int32
    // positional one-hot: aspect a (value 0..5) occupies bits [6a, 6a+6)
    plab[t] = (1u << ((unsigned)l.x & 31u))
            | (1u << (((unsigned)l.y & 31u) + 6u))
            | (1u << (((unsigned)l.z & 31u) + 12u))
            | (1u << (((unsigned)l.w & 31u) + 18u));
  }
  if (t < 2 * B_TOTAL) posAll[t] = 0.0f;   // posArr+allArr contiguous
}

// ---- fused sim/exp/mask/rowsum: barrier-free free-running waves -------------
template <int DIAG>
__device__ __forceinline__ void epi_n(
    const f32x4 (&acc)[2], int n, int colbase, int itBN, int l15,
    const unsigned int (&pi)[2][4], const int (&irow)[2][4],
    const unsigned int* __restrict__ plab_all,
    f32x2 (&pos2)[2][2], f32x2 (&all2)[2][2]) {
  const int j = colbase + n * 16 + l15;
  const unsigned int hj = plab_all[itBN + n * 16 + l15];
#pragma unroll
  for (int m = 0; m < 2; ++m) {
    float e[4];
#pragma unroll
    for (int q = 0; q < 4; ++q) {
      float v = __builtin_amdgcn_exp2f(acc[m][q]);   // acc already scaled
      if (DIAG) { if (j == irow[m][q]) v = 0.0f; }
      e[q] = v;
    }
    f32x2 p01 = { (pi[m][0] & hj) ? e[0] : 0.0f, (pi[m][1] & hj) ? e[1] : 0.0f };
    f32x2 p23 = { (pi[m][2] & hj) ? e[2] : 0.0f, (pi[m][3] & hj) ? e[3] : 0.0f };
    all2[m][0] += (f32x2){e[0], e[1]};
    all2[m][1] += (f32x2){e[2], e[3]};
    pos2[m][0] += p01;
    pos2[m][1] += p23;
  }
}

template <int DIAG>
__device__ __forceinline__ void iter_body(
    const unsigned char* __restrict__ Bf, int ctbase,
    const unsigned int* __restrict__ plab_all,
    const long (&afrag)[2][8], const unsigned int (&pi)[2][4],
    const int (&irow)[2][4], int colbase, int itBN, int l15, int lane,
    f32x2 (&pos2)[2][2], f32x2 (&all2)[2][2]) {
  auto loadB = [&](int n, lng2 (&b)[4]) {
    const unsigned char* p = Bf + (size_t)(ctbase + n) * 4096 + (unsigned)lane * 16u;
#pragma unroll
    for (int kw8 = 0; kw8 < 4; ++kw8) b[kw8] = *(const lng2*)(p + kw8 * 1024);
  };
  auto mfmaN = [&](const lng2 (&b)[4], f32x4 (&acc)[2]) {
    acc[0] = (f32x4){0.f, 0.f, 0.f, 0.f};
    acc[1] = (f32x4){0.f, 0.f, 0.f, 0.f};
#pragma unroll
    for (int kw8 = 0; kw8 < 4; ++kw8) {
      acc[0] = __builtin_amdgcn_mfma_f32_16x16x32_fp8_fp8(
          afrag[0][kw8 * 2], b[kw8][0], acc[0], 0, 0, 0);
      acc[1] = __builtin_amdgcn_mfma_f32_16x16x32_fp8_fp8(
          afrag[1][kw8 * 2], b[kw8][0], acc[1], 0, 0, 0);
      acc[0] = __builtin_amdgcn_mfma_f32_16x16x32_fp8_fp8(
          afrag[0][kw8 * 2 + 1], b[kw8][1], acc[0], 0, 0, 0);
      acc[1] = __builtin_amdgcn_mfma_f32_16x16x32_fp8_fp8(
          afrag[1][kw8 * 2 + 1], b[kw8][1], acc[1], 0, 0, 0);
    }
  };
  // software pipeline: loads 2 tiles ahead; epilogues fill MFMA/load latency
  lng2 b0[4], b1[4], b2_[4], b3[4];
  f32x4 accA[2], accB[2];
  loadB(0, b0); loadB(1, b1);
  mfmaN(b0, accA); loadB(2, b2_);
  mfmaN(b1, accB);
  epi_n<DIAG>(accA, 0, colbase, itBN, l15, pi, irow, plab_all, pos2, all2);
  mfmaN(b2_, accA); loadB(3, b3);
  epi_n<DIAG>(accB, 1, colbase, itBN, l15, pi, irow, plab_all, pos2, all2);
  mfmaN(b3, accB);
  epi_n<DIAG>(accA, 2, colbase, itBN, l15, pi, irow, plab_all, pos2, all2);
  epi_n<DIAG>(accB, 3, colbase, itBN, l15, pi, irow, plab_all, pos2, all2);
}

__global__ __launch_bounds__(256, 2) void main_kernel(
    const unsigned char* __restrict__ EbA, const unsigned char* __restrict__ Bf,
    const unsigned int* __restrict__ plab,
    float* __restrict__ posArr, float* __restrict__ allArr) {
  __shared__ unsigned int plab_all[COLS_PER];   // 2 KB: the only LDS
  const int tid = threadIdx.x;
  const int lane = tid & 63;
  const int wid = tid >> 6;        // 4 waves, each owns 32 rows
  const int l15 = lane & 15;
  const int l4 = lane >> 4;
  const int rb = (int)blockIdx.x & 63;   // 64 row-blocks of 128
  const int cs = (int)blockIdx.x >> 6;   // 16 column panels of 512
  const int rowbase = rb * BM;
  const int colstart = cs * COLS_PER;

  // A fragments: register-resident, 32 rows x 256 k per wave (32 VGPR in fp8)
  long afrag[2][8];
#pragma unroll
  for (int m = 0; m < 2; ++m) {
    const int row = rowbase + wid * 32 + m * 16 + l15;
    const unsigned char* rp = EbA + (size_t)row * DDIM + l4 * 64;
#pragma unroll
    for (int kw8 = 0; kw8 < 4; ++kw8) {
      lng2 t = *(const lng2*)(rp + kw8 * 16);
      afrag[m][kw8 * 2] = t[0];
      afrag[m][kw8 * 2 + 1] = t[1];
    }
  }

  // panel labels -> LDS once; the ONLY barrier in the kernel
  plab_all[tid] = plab[colstart + tid];
  plab_all[tid + 256] = plab[colstart + 256 + tid];

  unsigned int pi[2][4];
  int irow[2][4];
#pragma unroll
  for (int m = 0; m < 2; ++m)
#pragma unroll
    for (int q = 0; q < 4; ++q) {
      const int i = rowbase + wid * 32 + m * 16 + l4 * 4 + q;
      irow[m][q] = i;
      pi[m][q] = plab[i];
    }
  __syncthreads();

  f32x2 pos2[2][2] = {};
  f32x2 all2[2][2] = {};

  for (int it = 0; it < ITERS; ++it) {
    const int colbase = colstart + it * BN;
    const int ctbase = colbase >> 4;
    const bool hasDiag = (colbase < rowbase + BM) && (rowbase < colbase + BN);
    if (hasDiag)
      iter_body<1>(Bf, ctbase, plab_all, afrag, pi, irow,
                   colbase, it * BN, l15, lane, pos2, all2);
    else
      iter_body<0>(Bf, ctbase, plab_all, afrag, pi, irow,
                   colbase, it * BN, l15, lane, pos2, all2);
  }

  // reduce across the 16 lanes sharing the same rows, then one atomic per row
#pragma unroll
  for (int m = 0; m < 2; ++m)
#pragma unroll
    for (int q = 0; q < 4; ++q) {
      float p = pos2[m][q >> 1][q & 1], al = all2[m][q >> 1][q & 1];
      p += __shfl_xor(p, 1); p += __shfl_xor(p, 2);
      p += __shfl_xor(p, 4); p += __shfl_xor(p, 8);
      al += __shfl_xor(al, 1); al += __shfl_xor(al, 2);
      al += __shfl_xor(al, 4); al += __shfl_xor(al, 8);
      if (l15 == 0) {
        atomicAdd(&posArr[irow[m][q]], p);
        atomicAdd(&allArr[irow[m][q]], al);
      }
    }
}

// ---- finalize: row losses + mean (separate launch = free ordering) ----------
__global__ __launch_bounds__(1024) void finalize_kernel(
    const float* __restrict__ posArr, const float* __restrict__ allArr,
    float* __restrict__ out) {
  float ls = 0.f, cnt = 0.f;
#pragma unroll
  for (int k = 0; k < B_TOTAL / 1024; ++k) {
    const int i = threadIdx.x + (k << 10);
    const float p = posArr[i];
    const float a = allArr[i];
    if (p > 0.f) {
      ls += (__builtin_amdgcn_logf(a + 1e-8f) - __builtin_amdgcn_logf(p)) * LN2F;
      cnt += 1.f;
    }
  }
#pragma unroll
  for (int msk = 1; msk < 64; msk <<= 1) {
    ls += __shfl_xor(ls, msk);
    cnt += __shfl_xor(cnt, msk);
  }
  __shared__ float sls[16], scnt[16];
  const int w = threadIdx.x >> 6;
  if ((threadIdx.x & 63) == 0) { sls[w] = ls; scnt[w] = cnt; }
  __syncthreads();
  if (threadIdx.x == 0) {
    float L = 0.f, C = 0.f;
    for (int i = 0; i < 16; ++i) { L += sls[i]; C += scnt[i]; }
    out[0] = (C > 0.f) ? L / fmaxf(C, 1.f) : 0.f;
  }
}

// ---- launch -----------------------------------------------------------------
extern "C" void kernel_launch(void* const* d_in, const int* in_sizes, int n_in,
                              void* d_out, int out_size, void* d_ws, size_t ws_size,
                              hipStream_t stream) {
  const float* E = (const float*)d_in[0];
  const int* lab = (const int*)d_in[1];
  float* out = (float*)d_out;
  char* ws = (char*)d_ws;

  unsigned char* EbA = (unsigned char*)ws;                        // 2 MB
  unsigned char* Bf = (unsigned char*)(ws + 2u * 1024u * 1024u);  // 2 MB
  unsigned int* plab = (unsigned int*)(ws + 4u * 1024u * 1024u);  // 32 KB
  float* posArr = (float*)(ws + 4u * 1024u * 1024u + 32u * 1024u);
  float* allArr = posArr + B_TOTAL;

  prep_all<<<1024, 256, 0, stream>>>(E, lab, EbA, Bf, plab, posArr);
  main_kernel<<<NBLOCKS, 256, 0, stream>>>(EbA, Bf, plab, posArr, allArr);
  finalize_kernel<<<1, 1024, 0, stream>>>(posArr, allArr, out);
}